// Round 1
// baseline (958.778 us; speedup 1.0000x reference)
//
#include <hip/hip_runtime.h>

#define NUM_USERS 200000
#define NUM_ITEMS 100000
#define N_NODES   300000
#define NNZ       4000000
#define DIM       64
#define N_ELEM   ((size_t)N_NODES * DIM)   // 19,200,000 elements

#define NSUB      8                        // per-XCD sub-frontiers
#define NROWBLK   ((N_NODES + 255) / 256)  // 1172 row-groups for the scan

typedef unsigned int uint32;

// bf16 <-> fp32 helpers (finite values only; RNE rounding)
static __device__ __forceinline__ unsigned short f2bf(float f) {
    unsigned int u = __float_as_uint(f);
    u = (u + 0x7FFF + ((u >> 16) & 1)) >> 16;   // round-to-nearest-even
    return (unsigned short)u;
}

// ---------------------------------------------------------------------------
// K0: convert concat(user,item) fp32 -> bf16 bufC (float4 in, ushort4 out)
// ---------------------------------------------------------------------------
__global__ void lgcn_convert(const float4* __restrict__ user4,
                             const float4* __restrict__ item4,
                             ushort4* __restrict__ bufC) {
    size_t i = (size_t)blockIdx.x * blockDim.x + threadIdx.x;
    const size_t n4 = N_ELEM / 4, nu4 = (size_t)NUM_USERS * DIM / 4;
    if (i >= n4) return;
    float4 v = (i < nu4) ? user4[i] : item4[i - nu4];
    ushort4 o;
    o.x = f2bf(v.x); o.y = f2bf(v.y); o.z = f2bf(v.z); o.w = f2bf(v.w);
    bufC[i] = o;
}

// ---------------------------------------------------------------------------
// K1: per-(g,row) histogram. g = (e>>10)&7 == blockIdx&7 at BLK=256 (XCD id
// under round-robin dispatch), so cnt[g][*] lines are only ever touched by
// XCD g -> no cross-XCD atomic ping-pong, no padding needed ([g][row] layout:
// a 64B line holds 16 rows of ONE g).
// ---------------------------------------------------------------------------
__global__ void lgcn_rhist(const int4* __restrict__ rows4, int* __restrict__ cnt) {
    int i = blockIdx.x * blockDim.x + threadIdx.x;
    if (i >= NNZ / 4) return;
    int g = (i >> 8) & (NSUB - 1);          // == (e>>10)&7 for e in {4i..4i+3}
    int* c = cnt + g * N_NODES;
    int4 r = rows4[i];
    atomicAdd(&c[r.x], 1);
    atomicAdd(&c[r.y], 1);
    atomicAdd(&c[r.z], 1);
    atomicAdd(&c[r.w], 1);
}

// ---------------------------------------------------------------------------
// K2: row allocation. One thread per row: sums its 8 g-counts, wave-scan +
// one cursor atomic per wave (order-free, same pattern as old balloc), writes
// desc[row]=(base,tot) and ABSOLUTE cursors fill[g][row] so the scatter can
// write edges directly to their final sc position. Rows within a 64-lane
// wave get contiguous spans -> SpMM's 4-row blocks still read dense sc.
// ---------------------------------------------------------------------------
__global__ void lgcn_rscan(const int* __restrict__ cnt, int2* __restrict__ desc,
                           int* __restrict__ fill, int* __restrict__ cursor) {
    int row  = blockIdx.x * blockDim.x + threadIdx.x;
    int lane = threadIdx.x & 63;
    int cg[NSUB];
    int tot = 0;
    if (row < N_NODES) {
        #pragma unroll
        for (int g = 0; g < NSUB; ++g) {
            cg[g] = cnt[g * N_NODES + row];   // coalesced per-g (lane==row)
            tot += cg[g];
        }
    }
    int s = tot;
    #pragma unroll
    for (int o = 1; o < 64; o <<= 1) {
        int t = __shfl_up(s, o);
        if (lane >= o) s += t;
    }
    int wtot = __shfl(s, 63);
    int wbase = 0;
    if (lane == 63) wbase = atomicAdd(cursor, wtot);
    wbase = __shfl(wbase, 63);
    if (row < N_NODES) {
        int base = wbase + (s - tot);
        desc[row] = make_int2(base, tot);
        int run = base;
        #pragma unroll
        for (int g = 0; g < NSUB; ++g) {
            fill[g * N_NODES + row] = run;
            run += cg[g];
        }
    }
}

// ---------------------------------------------------------------------------
// K3: single-pass scatter to FINAL row-sorted position (replaces append+bsort).
// int4 form: 4 independent atomic->store chains per lane (4x MLP in a kernel
// that is 99% memory-wait). g = (i>>8)&7 == blockIdx&7 -> atomics stay in the
// issuing XCD's L2 slice of fill.
// ---------------------------------------------------------------------------
__global__ void lgcn_scatter(const int4* __restrict__ rows4,
                             const int4* __restrict__ cols4,
                             const float4* __restrict__ vals4,
                             int* __restrict__ fill, int2* __restrict__ sc) {
    int i = blockIdx.x * blockDim.x + threadIdx.x;
    if (i >= NNZ / 4) return;
    int g = (i >> 8) & (NSUB - 1);
    int* f = fill + g * N_NODES;
    int4   r = rows4[i];
    int4   c = cols4[i];
    float4 v = vals4[i];
    int p0 = atomicAdd(&f[r.x], 1);
    int p1 = atomicAdd(&f[r.y], 1);
    int p2 = atomicAdd(&f[r.z], 1);
    int p3 = atomicAdd(&f[r.w], 1);
    sc[p0] = make_int2(c.x, __float_as_int(v.x));
    sc[p1] = make_int2(c.y, __float_as_int(v.y));
    sc[p2] = make_int2(c.z, __float_as_int(v.z));
    sc[p3] = make_int2(c.w, __float_as_int(v.w));
}

// ---------------------------------------------------------------------------
// Paired-edge CSR SpMM (unchanged). One wave per row; lane = dim-PAIR
// (hl=lane&31 covers dims 2hl,2hl+1 as one uint bf16x2). Low half-wave
// processes edge j, high half edge j+1 -> each gather instr moves 256 B
// (2 rows). Halves combined at the end with __shfl_xor(,32). Edges padded to
// x16 with (col=0,val=0) pad lanes (hot row-0 line, x*0).
// MODE 1: nxt2 = bf16x2(acc)                                 (layers 1,2)
// MODE 2: out2 = 0.25*(own + e1 + e2 + acc)  fp32            (layer 3)
// ---------------------------------------------------------------------------
template<int MODE>
__global__ __launch_bounds__(256) void lgcn_spmm_csr(
    const int2* __restrict__ desc, const int2* __restrict__ sc,
    const uint32* __restrict__ cur2, uint32* __restrict__ nxt2,
    const float2* __restrict__ user2, const float2* __restrict__ item2,
    const uint32* __restrict__ e1b, const uint32* __restrict__ e2b,
    float2* __restrict__ out2)
{
    int row  = blockIdx.x * 4 + (threadIdx.x >> 6);
    int lane = threadIdx.x & 63;
    if (row >= N_NODES) return;
    int2 d = desc[row];
    int b = d.x, n = d.y;
    int half = lane >> 5;          // which edge of the pair
    int hl   = lane & 31;          // dim-pair index
    float accA_lo = 0.f, accA_hi = 0.f, accB_lo = 0.f, accB_hi = 0.f;

    for (int k0 = 0; k0 < n; k0 += 64) {
        int m = min(64, n - k0);
        int c = 0, vbits = 0;
        if (lane < m) {
            int2 cv = sc[b + k0 + lane];
            c = cv.x; vbits = cv.y;
        }
        int m16 = (m + 15) & ~15;
        for (int j = 0; j < m16; j += 16) {
            int    idx[8];
            float  vv[8];
            uint32 x[8];
            #pragma unroll
            for (int t = 0; t < 8; ++t) {
                int src = j + 2 * t + half;          // <= 63 always
                idx[t] = __shfl(c, src);
                vv[t]  = __int_as_float(__shfl(vbits, src));
            }
            #pragma unroll
            for (int t = 0; t < 8; ++t)
                x[t] = cur2[idx[t] * 32 + hl];
            #pragma unroll
            for (int t = 0; t < 8; ++t) {
                float xlo = __uint_as_float(x[t] << 16);
                float xhi = __uint_as_float(x[t] & 0xFFFF0000u);
                if (t & 1) { accB_lo += vv[t] * xlo; accB_hi += vv[t] * xhi; }
                else       { accA_lo += vv[t] * xlo; accA_hi += vv[t] * xhi; }
            }
        }
    }

    float alo = accA_lo + accB_lo;
    float ahi = accA_hi + accB_hi;
    alo += __shfl_xor(alo, 32);    // combine the two half-wave edge subsets
    ahi += __shfl_xor(ahi, 32);

    if (half == 0) {
        int off = row * 32 + hl;
        if constexpr (MODE == 1) {
            nxt2[off] = ((uint32)f2bf(ahi) << 16) | (uint32)f2bf(alo);
        } else {
            float2 own = (row < NUM_USERS) ? user2[off]
                                           : item2[(row - NUM_USERS) * 32 + hl];
            uint32 e1 = e1b[off], e2 = e2b[off];
            float2 o;
            o.x = 0.25f * (own.x + __uint_as_float(e1 << 16)
                                 + __uint_as_float(e2 << 16) + alo);
            o.y = 0.25f * (own.y + __uint_as_float(e1 & 0xFFFF0000u)
                                 + __uint_as_float(e2 & 0xFFFF0000u) + ahi);
            out2[off] = o;
        }
    }
}

extern "C" void kernel_launch(void* const* d_in, const int* in_sizes, int n_in,
                              void* d_out, int out_size, void* d_ws, size_t ws_size,
                              hipStream_t stream) {
    const float* user_emb = (const float*)d_in[0];
    const float* item_emb = (const float*)d_in[1];
    const float* vals     = (const float*)d_in[2];
    const int*   rows     = (const int*)d_in[3];
    const int*   cols     = (const int*)d_in[4];
    float* out = (float*)d_out;

    // ---- workspace carve-up (~169 MB) ----
    char* ws = (char*)d_ws;
    size_t off = 0;
    unsigned short* bufC = (unsigned short*)(ws + off); off += N_ELEM * 2;      // 38.4 MB
    unsigned short* buf0 = (unsigned short*)(ws + off); off += N_ELEM * 2;      // 38.4 MB
    unsigned short* buf1 = (unsigned short*)(ws + off); off += N_ELEM * 2;      // 38.4 MB
    int2* sc      = (int2*)(ws + off); off += (size_t)NNZ * 8;                  // 32 MB
    int2* desc    = (int2*)(ws + off); off += (size_t)N_NODES * 8;              // 2.4 MB
    int*  cnt     = (int*) (ws + off); off += (size_t)NSUB * N_NODES * 4;       // 9.6 MB
    int*  cursor  = (int*) (ws + off); off += 256;                              // w/ cnt memset
    int*  fill    = (int*) (ws + off); off += (size_t)NSUB * N_NODES * 4;       // 9.6 MB

    const int BLK = 256;
    dim3 grid_conv((unsigned)((N_ELEM / 4 + BLK - 1) / BLK));   // 18750
    dim3 grid_e4((NNZ / 4 + BLK - 1) / BLK);                    // 3907
    dim3 grid_scan(NROWBLK);                                    // 1172
    dim3 grid_spmm((N_NODES + 3) / 4);                          // 75000

    // ---- build (once per call; ws re-poisoned before every launch) ----
    hipMemsetAsync(cnt, 0, (size_t)NSUB * N_NODES * 4 + 256, stream); // cnt+cursor
    lgcn_convert<<<grid_conv, BLK, 0, stream>>>(
        (const float4*)user_emb, (const float4*)item_emb, (ushort4*)bufC);
    lgcn_rhist<<<grid_e4, BLK, 0, stream>>>((const int4*)rows, cnt);
    lgcn_rscan<<<grid_scan, BLK, 0, stream>>>(cnt, desc, fill, cursor);
    lgcn_scatter<<<grid_e4, BLK, 0, stream>>>(
        (const int4*)rows, (const int4*)cols, (const float4*)vals, fill, sc);

    // ---- 3 propagation layers ----
    lgcn_spmm_csr<1><<<grid_spmm, BLK, 0, stream>>>(
        desc, sc, (const uint32*)bufC, (uint32*)buf0,
        nullptr, nullptr, nullptr, nullptr, nullptr);
    lgcn_spmm_csr<1><<<grid_spmm, BLK, 0, stream>>>(
        desc, sc, (const uint32*)buf0, (uint32*)buf1,
        nullptr, nullptr, nullptr, nullptr, nullptr);
    lgcn_spmm_csr<2><<<grid_spmm, BLK, 0, stream>>>(
        desc, sc, (const uint32*)buf1, nullptr,
        (const float2*)user_emb, (const float2*)item_emb,
        (const uint32*)buf0, (const uint32*)buf1, (float2*)out);
}

// Round 2
// 897.867 us; speedup vs baseline: 1.0678x; 1.0678x over previous
//
#include <hip/hip_runtime.h>

#define NUM_USERS 200000
#define NUM_ITEMS 100000
#define N_NODES   300000
#define NNZ       4000000
#define DIM       64
#define N_ELEM   ((size_t)N_NODES * DIM)   // 19,200,000 elements

#define BKT_SHIFT 8                        // 256 rows per bucket
#define BKT_ROWS  256
#define NBKT      ((N_NODES + BKT_ROWS - 1) >> BKT_SHIFT)   // 1172
#define NSUB      8                        // per-XCD sub-frontiers per bucket
#define PAD       32                       // pad atomic counters to 128B lines

typedef unsigned int uint32;

// bf16 <-> fp32 helpers (finite values only; RNE rounding)
static __device__ __forceinline__ unsigned short f2bf(float f) {
    unsigned int u = __float_as_uint(f);
    u = (u + 0x7FFF + ((u >> 16) & 1)) >> 16;   // round-to-nearest-even
    return (unsigned short)u;
}
static __device__ __forceinline__ float blo(uint32 w) { return __uint_as_float(w << 16); }
static __device__ __forceinline__ float bhi(uint32 w) { return __uint_as_float(w & 0xFFFF0000u); }

// ---------------------------------------------------------------------------
// K0: convert concat(user,item) fp32 -> bf16 bufC (float4 in, ushort4 out)
// ---------------------------------------------------------------------------
__global__ void lgcn_convert(const float4* __restrict__ user4,
                             const float4* __restrict__ item4,
                             ushort4* __restrict__ bufC) {
    size_t i = (size_t)blockIdx.x * blockDim.x + threadIdx.x;
    const size_t n4 = N_ELEM / 4, nu4 = (size_t)NUM_USERS * DIM / 4;
    if (i >= n4) return;
    float4 v = (i < nu4) ? user4[i] : item4[i - nu4];
    ushort4 o;
    o.x = f2bf(v.x); o.y = f2bf(v.y); o.z = f2bf(v.z); o.w = f2bf(v.w);
    bufC[i] = o;
}

// ---------------------------------------------------------------------------
// K1: (bucket, group) histogram. g must equal append's g = blockIdx&7 with
// BLK=256 -> g = (e>>8)&7 = (i>>6)&7 for int4 index i.
// ---------------------------------------------------------------------------
__global__ void lgcn_bhist(const int4* __restrict__ rows4, int* __restrict__ bcnt) {
    int i = blockIdx.x * blockDim.x + threadIdx.x;
    if (i >= NNZ / 4) return;
    int g = (i >> 6) & (NSUB - 1);
    int4 r = rows4[i];
    atomicAdd(&bcnt[(((r.x >> BKT_SHIFT) << 3) + g) * PAD], 1);
    atomicAdd(&bcnt[(((r.y >> BKT_SHIFT) << 3) + g) * PAD], 1);
    atomicAdd(&bcnt[(((r.z >> BKT_SHIFT) << 3) + g) * PAD], 1);
    atomicAdd(&bcnt[(((r.w >> BKT_SHIFT) << 3) + g) * PAD], 1);
}

// ---------------------------------------------------------------------------
// K2: segment allocation. One thread per bucket: sums its 8 sub-counts,
// wave-scan + one cursor atomic per wave (order-free), lays sub-segments
// contiguously so bucket span = [bbase[b], bbase[b]+btot[b]).
// ---------------------------------------------------------------------------
__global__ void lgcn_balloc(const int* __restrict__ bcnt, int* __restrict__ bbase,
                            int* __restrict__ btot, int* __restrict__ bfill,
                            int* __restrict__ cursor) {
    int b = blockIdx.x * blockDim.x + threadIdx.x;
    int lane = threadIdx.x & 63;
    int cg[NSUB];
    int tot = 0;
    if (b < NBKT) {
        #pragma unroll
        for (int g = 0; g < NSUB; ++g) {
            cg[g] = bcnt[((b << 3) + g) * PAD];
            tot += cg[g];
        }
    }
    int s = tot;
    #pragma unroll
    for (int o = 1; o < 64; o <<= 1) {
        int t = __shfl_up(s, o);
        if (lane >= o) s += t;
    }
    int wtot = __shfl(s, 63);
    int wbase = 0;
    if (lane == 63) wbase = atomicAdd(cursor, wtot);
    wbase = __shfl(wbase, 63);
    if (b < NBKT) {
        int base = wbase + (s - tot);
        bbase[b] = base;
        btot[b]  = tot;
        int run = base;
        #pragma unroll
        for (int g = 0; g < NSUB; ++g) {
            bfill[((b << 3) + g) * PAD] = run;
            run += cg[g];
        }
    }
}

// ---------------------------------------------------------------------------
// K3: append edges to the (bucket, g) sub-frontier, g = blockIdx&7 (XCD id
// under round-robin dispatch). Frontier = 1172 lines (~150 KB) per XCD.
// staging element = { (local_row<<19) | col , val_bits }  (col<2^19, lr<256)
// ---------------------------------------------------------------------------
__global__ void lgcn_append(const int* __restrict__ rows, const int* __restrict__ cols,
                            const float* __restrict__ vals, int* __restrict__ bfill,
                            int2* __restrict__ staging) {
    int e = blockIdx.x * blockDim.x + threadIdx.x;
    if (e >= NNZ) return;
    int g = blockIdx.x & (NSUB - 1);
    int r = rows[e];
    int b = r >> BKT_SHIFT;
    int p = atomicAdd(&bfill[((b << 3) + g) * PAD], 1);
    staging[p] = make_int2(((r & (BKT_ROWS - 1)) << 19) | cols[e],
                           __float_as_int(vals[e]));
}

// ---------------------------------------------------------------------------
// K4: per-bucket LDS sort (256 local rows). Count, block-scan (Hillis-Steele
// in LDS), emit desc[row], then re-read the (L2-hot) bucket span and write
// row-sorted sc. Each workgroup owns its span exclusively -> dense writes.
// ---------------------------------------------------------------------------
__global__ __launch_bounds__(256) void lgcn_bsort(
    const int2* __restrict__ staging, const int* __restrict__ bbase,
    const int* __restrict__ btot, int2* __restrict__ desc, int2* __restrict__ sc)
{
    __shared__ int cnt[BKT_ROWS], pfx[BKT_ROWS], fill[BKT_ROWS];
    int b   = blockIdx.x;
    int tid = threadIdx.x;
    cnt[tid] = 0;
    __syncthreads();
    int base = bbase[b];
    int n    = btot[b];

    // Phase A: count local rows
    for (int i = tid; i < n; i += 256)
        atomicAdd(&cnt[staging[base + i].x >> 19], 1);
    __syncthreads();

    // Phase B: block-wide inclusive scan of 256 counts
    int c = cnt[tid];
    pfx[tid] = c;
    __syncthreads();
    for (int o = 1; o < 256; o <<= 1) {
        int t = (tid >= o) ? pfx[tid - o] : 0;
        __syncthreads();
        pfx[tid] += t;
        __syncthreads();
    }
    int excl = pfx[tid] - c;
    fill[tid] = excl;                       // relative to base
    int row = (b << BKT_SHIFT) + tid;
    if (row < N_NODES) desc[row] = make_int2(base + excl, c);
    __syncthreads();

    // Phase C: scatter into row-sorted order within the exclusive bucket span
    for (int i = tid; i < n; i += 256) {
        int2 e = staging[base + i];
        int lr = e.x >> 19;
        int p = atomicAdd(&fill[lr], 1);
        sc[base + p] = make_int2(e.x & 0x7FFFF, e.y);
    }
}

// ---------------------------------------------------------------------------
// Wide-gather CSR SpMM. One wave per row; 8 subgroups (q=lane>>3) x 8 lanes
// (gl=lane&7). Lane gl of subgroup q loads uint4 chunk gl (16B) of the row
// gathered for edge-slot (j + q) / (j + 8 + q): ONE dwordx4 instruction moves
// 8 rows x 128B = 1KB (vs 256B for the old dword gather -> 4x fewer gather
// instrs, 4x bytes per load slot in this latency-bound kernel). Lane owns dim
// pairs gl*4+p (p=0..3); A/B accumulator chains per edge-parity; 3-step
// shfl_xor(8/16/32) butterfly combines the 8 subgroups at the end.
// Edges padded to x16 with (col=0,val=0) pad lanes (hot row-0 line, x*0).
// MODE 1: nxt = bf16x8(acc)            uint4 store   (layers 1,2)
// MODE 2: out = 0.25*(own+e1+e2+acc)   2x float4     (layer 3)
// ---------------------------------------------------------------------------
template<int MODE>
__global__ __launch_bounds__(256) void lgcn_spmm_csr(
    const int2* __restrict__ desc, const int2* __restrict__ sc,
    const uint4* __restrict__ cur4, uint4* __restrict__ nxt4,
    const float4* __restrict__ user4, const float4* __restrict__ item4,
    const uint4* __restrict__ e1b4, const uint4* __restrict__ e2b4,
    float4* __restrict__ out4)
{
    int row  = blockIdx.x * 4 + (threadIdx.x >> 6);
    int lane = threadIdx.x & 63;
    if (row >= N_NODES) return;
    int2 d = desc[row];
    int b = d.x, n = d.y;
    int q  = lane >> 3;            // edge-slot subgroup
    int gl = lane & 7;             // 16B chunk of the gathered row
    float aAlo[4] = {0.f, 0.f, 0.f, 0.f}, aAhi[4] = {0.f, 0.f, 0.f, 0.f};
    float aBlo[4] = {0.f, 0.f, 0.f, 0.f}, aBhi[4] = {0.f, 0.f, 0.f, 0.f};

    for (int k0 = 0; k0 < n; k0 += 64) {
        int m = min(64, n - k0);
        int c = 0, vbits = 0;
        if (lane < m) {
            int2 cv = sc[b + k0 + lane];
            c = cv.x; vbits = cv.y;
        }
        int m16 = (m + 15) & ~15;
        for (int j = 0; j < m16; j += 16) {
            int   i0 = __shfl(c, j + q);
            int   i1 = __shfl(c, j + 8 + q);
            float v0 = __int_as_float(__shfl(vbits, j + q));
            float v1 = __int_as_float(__shfl(vbits, j + 8 + q));
            uint4 x0 = cur4[i0 * 8 + gl];
            uint4 x1 = cur4[i1 * 8 + gl];
            aAlo[0] += v0 * blo(x0.x); aAhi[0] += v0 * bhi(x0.x);
            aAlo[1] += v0 * blo(x0.y); aAhi[1] += v0 * bhi(x0.y);
            aAlo[2] += v0 * blo(x0.z); aAhi[2] += v0 * bhi(x0.z);
            aAlo[3] += v0 * blo(x0.w); aAhi[3] += v0 * bhi(x0.w);
            aBlo[0] += v1 * blo(x1.x); aBhi[0] += v1 * bhi(x1.x);
            aBlo[1] += v1 * blo(x1.y); aBhi[1] += v1 * bhi(x1.y);
            aBlo[2] += v1 * blo(x1.z); aBhi[2] += v1 * bhi(x1.z);
            aBlo[3] += v1 * blo(x1.w); aBhi[3] += v1 * bhi(x1.w);
        }
    }

    float rlo[4], rhi[4];
    #pragma unroll
    for (int p = 0; p < 4; ++p) {
        rlo[p] = aAlo[p] + aBlo[p];
        rhi[p] = aAhi[p] + aBhi[p];
    }
    #pragma unroll
    for (int o = 8; o < 64; o <<= 1) {
        #pragma unroll
        for (int p = 0; p < 4; ++p) {
            rlo[p] += __shfl_xor(rlo[p], o);
            rhi[p] += __shfl_xor(rhi[p], o);
        }
    }

    if (lane < 8) {                // q == 0, gl == lane
        if constexpr (MODE == 1) {
            uint4 o;
            o.x = ((uint32)f2bf(rhi[0]) << 16) | (uint32)f2bf(rlo[0]);
            o.y = ((uint32)f2bf(rhi[1]) << 16) | (uint32)f2bf(rlo[1]);
            o.z = ((uint32)f2bf(rhi[2]) << 16) | (uint32)f2bf(rlo[2]);
            o.w = ((uint32)f2bf(rhi[3]) << 16) | (uint32)f2bf(rlo[3]);
            nxt4[row * 8 + gl] = o;
        } else {
            const float4* own4 = (row < NUM_USERS)
                ? user4 + (size_t)row * 16
                : item4 + (size_t)(row - NUM_USERS) * 16;
            float4 w0 = own4[gl * 2], w1 = own4[gl * 2 + 1];
            uint4 e1 = e1b4[row * 8 + gl], e2 = e2b4[row * 8 + gl];
            float4 o0, o1;
            o0.x = 0.25f * (w0.x + blo(e1.x) + blo(e2.x) + rlo[0]);
            o0.y = 0.25f * (w0.y + bhi(e1.x) + bhi(e2.x) + rhi[0]);
            o0.z = 0.25f * (w0.z + blo(e1.y) + blo(e2.y) + rlo[1]);
            o0.w = 0.25f * (w0.w + bhi(e1.y) + bhi(e2.y) + rhi[1]);
            o1.x = 0.25f * (w1.x + blo(e1.z) + blo(e2.z) + rlo[2]);
            o1.y = 0.25f * (w1.y + bhi(e1.z) + bhi(e2.z) + rhi[2]);
            o1.z = 0.25f * (w1.z + blo(e1.w) + blo(e2.w) + rlo[3]);
            o1.w = 0.25f * (w1.w + bhi(e1.w) + bhi(e2.w) + rhi[3]);
            out4[(size_t)row * 16 + gl * 2]     = o0;
            out4[(size_t)row * 16 + gl * 2 + 1] = o1;
        }
    }
}

extern "C" void kernel_launch(void* const* d_in, const int* in_sizes, int n_in,
                              void* d_out, int out_size, void* d_ws, size_t ws_size,
                              hipStream_t stream) {
    const float* user_emb = (const float*)d_in[0];
    const float* item_emb = (const float*)d_in[1];
    const float* vals     = (const float*)d_in[2];
    const int*   rows     = (const int*)d_in[3];
    const int*   cols     = (const int*)d_in[4];
    float* out = (float*)d_out;

    // ---- workspace carve-up (~185 MB) ----
    char* ws = (char*)d_ws;
    size_t off = 0;
    unsigned short* bufC = (unsigned short*)(ws + off); off += N_ELEM * 2;      // 38.4 MB
    unsigned short* buf0 = (unsigned short*)(ws + off); off += N_ELEM * 2;      // 38.4 MB
    unsigned short* buf1 = (unsigned short*)(ws + off); off += N_ELEM * 2;      // 38.4 MB
    int2* staging = (int2*)(ws + off); off += (size_t)NNZ * 8;                  // 32 MB
    int2* sc      = (int2*)(ws + off); off += (size_t)NNZ * 8;                  // 32 MB
    int2* desc    = (int2*)(ws + off); off += (size_t)N_NODES * 8;              // 2.4 MB
    int*  bcnt    = (int*) (ws + off); off += (size_t)NBKT * NSUB * PAD * 4;    // 1.2 MB
    int*  cursor  = (int*) (ws + off); off += 256;                              // w/ bcnt memset
    int*  bbase   = (int*) (ws + off); off += (size_t)NBKT * 4;
    int*  btot    = (int*) (ws + off); off += (size_t)NBKT * 4;
    int*  bfill   = (int*) (ws + off); off += (size_t)NBKT * NSUB * PAD * 4;    // 1.2 MB

    const int BLK = 256;
    dim3 grid_conv((unsigned)((N_ELEM / 4 + BLK - 1) / BLK));   // 18750
    dim3 grid_edge((NNZ + BLK - 1) / BLK);                      // 15625
    dim3 grid_edge4((NNZ / 4 + BLK - 1) / BLK);                 // 3907
    dim3 grid_bkt((NBKT + BLK - 1) / BLK);                      // 5
    dim3 grid_sort(NBKT);                                       // 1172
    dim3 grid_spmm((N_NODES + 3) / 4);                          // 75000

    // ---- build (once per call; ws re-poisoned before every launch) ----
    hipMemsetAsync(bcnt, 0, (size_t)NBKT * NSUB * PAD * 4 + 256, stream); // bcnt+cursor
    lgcn_convert<<<grid_conv, BLK, 0, stream>>>(
        (const float4*)user_emb, (const float4*)item_emb, (ushort4*)bufC);
    lgcn_bhist<<<grid_edge4, BLK, 0, stream>>>((const int4*)rows, bcnt);
    lgcn_balloc<<<grid_bkt, BLK, 0, stream>>>(bcnt, bbase, btot, bfill, cursor);
    lgcn_append<<<grid_edge, BLK, 0, stream>>>(rows, cols, vals, bfill, staging);
    lgcn_bsort<<<grid_sort, BLK, 0, stream>>>(staging, bbase, btot, desc, sc);

    // ---- 3 propagation layers ----
    lgcn_spmm_csr<1><<<grid_spmm, BLK, 0, stream>>>(
        desc, sc, (const uint4*)bufC, (uint4*)buf0,
        nullptr, nullptr, nullptr, nullptr, nullptr);
    lgcn_spmm_csr<1><<<grid_spmm, BLK, 0, stream>>>(
        desc, sc, (const uint4*)buf0, (uint4*)buf1,
        nullptr, nullptr, nullptr, nullptr, nullptr);
    lgcn_spmm_csr<2><<<grid_spmm, BLK, 0, stream>>>(
        desc, sc, (const uint4*)buf1, nullptr,
        (const float4*)user_emb, (const float4*)item_emb,
        (const uint4*)buf0, (const uint4*)buf1, (float4*)out);
}

// Round 4
// 798.826 us; speedup vs baseline: 1.2002x; 1.1240x over previous
//
#include <hip/hip_runtime.h>

#define NUM_USERS 200000
#define NUM_ITEMS 100000
#define N_NODES   300000
#define NNZ       4000000
#define DIM       64
#define N_ELEM   ((size_t)N_NODES * DIM)   // 19,200,000 elements

#define BKT_SHIFT 8                        // 256 rows per bucket
#define BKT_ROWS  256
#define NBKT      ((N_NODES + BKT_ROWS - 1) >> BKT_SHIFT)   // 1172
#define NSUB      8                        // per-XCD sub-frontiers per bucket
#define PAD       32                       // pad atomic counters to 128B lines

typedef unsigned int uint32;

// Native clang vector types: __builtin_nontemporal_load rejects the
// HIP_vector_type structs (round-3 compile failure) but accepts these.
typedef __attribute__((ext_vector_type(4))) float         nfloat4;
typedef __attribute__((ext_vector_type(4))) int           nint4;
typedef __attribute__((ext_vector_type(2))) int           nint2;
typedef __attribute__((ext_vector_type(2))) unsigned int  nuint2;

static __device__ __forceinline__ float4 ntload(const float4* p) {
    nfloat4 v = __builtin_nontemporal_load(reinterpret_cast<const nfloat4*>(p));
    return make_float4(v.x, v.y, v.z, v.w);
}
static __device__ __forceinline__ int4 ntload(const int4* p) {
    nint4 v = __builtin_nontemporal_load(reinterpret_cast<const nint4*>(p));
    return make_int4(v.x, v.y, v.z, v.w);
}
static __device__ __forceinline__ int2 ntload(const int2* p) {
    nint2 v = __builtin_nontemporal_load(reinterpret_cast<const nint2*>(p));
    return make_int2(v.x, v.y);
}
static __device__ __forceinline__ uint2 ntload(const uint2* p) {
    nuint2 v = __builtin_nontemporal_load(reinterpret_cast<const nuint2*>(p));
    return make_uint2(v.x, v.y);
}

// bf16 <-> fp32 helpers (finite values only; RNE rounding)
static __device__ __forceinline__ unsigned short f2bf(float f) {
    unsigned int u = __float_as_uint(f);
    u = (u + 0x7FFF + ((u >> 16) & 1)) >> 16;   // round-to-nearest-even
    return (unsigned short)u;
}
static __device__ __forceinline__ float blo(uint32 w) { return __uint_as_float(w << 16); }
static __device__ __forceinline__ float bhi(uint32 w) { return __uint_as_float(w & 0xFFFF0000u); }

// ---------------------------------------------------------------------------
// K0: convert concat(user,item) fp32 -> bf16 bufC. NT loads: the fp32 inputs
// are read-once streams; keep them out of L2 (bufC store stays cached -- it
// is the layer-1 gather target).
// ---------------------------------------------------------------------------
__global__ void lgcn_convert(const float4* __restrict__ user4,
                             const float4* __restrict__ item4,
                             ushort4* __restrict__ bufC) {
    size_t i = (size_t)blockIdx.x * blockDim.x + threadIdx.x;
    const size_t n4 = N_ELEM / 4, nu4 = (size_t)NUM_USERS * DIM / 4;
    if (i >= n4) return;
    float4 v = (i < nu4) ? ntload(&user4[i]) : ntload(&item4[i - nu4]);
    ushort4 o;
    o.x = f2bf(v.x); o.y = f2bf(v.y); o.z = f2bf(v.z); o.w = f2bf(v.w);
    bufC[i] = o;
}

// ---------------------------------------------------------------------------
// K1: (bucket, group) histogram. g must equal append's g = blockIdx&7 with
// BLK=256 -> g = (e>>8)&7 = (i>>6)&7 for int4 index i.
// ---------------------------------------------------------------------------
__global__ void lgcn_bhist(const int4* __restrict__ rows4, int* __restrict__ bcnt) {
    int i = blockIdx.x * blockDim.x + threadIdx.x;
    if (i >= NNZ / 4) return;
    int g = (i >> 6) & (NSUB - 1);
    int4 r = ntload(&rows4[i]);
    atomicAdd(&bcnt[(((r.x >> BKT_SHIFT) << 3) + g) * PAD], 1);
    atomicAdd(&bcnt[(((r.y >> BKT_SHIFT) << 3) + g) * PAD], 1);
    atomicAdd(&bcnt[(((r.z >> BKT_SHIFT) << 3) + g) * PAD], 1);
    atomicAdd(&bcnt[(((r.w >> BKT_SHIFT) << 3) + g) * PAD], 1);
}

// ---------------------------------------------------------------------------
// K2: segment allocation. One thread per bucket: sums its 8 sub-counts,
// wave-scan + one cursor atomic per wave (order-free), lays sub-segments
// contiguously so bucket span = [bbase[b], bbase[b]+btot[b]).
// ---------------------------------------------------------------------------
__global__ void lgcn_balloc(const int* __restrict__ bcnt, int* __restrict__ bbase,
                            int* __restrict__ btot, int* __restrict__ bfill,
                            int* __restrict__ cursor) {
    int b = blockIdx.x * blockDim.x + threadIdx.x;
    int lane = threadIdx.x & 63;
    int cg[NSUB];
    int tot = 0;
    if (b < NBKT) {
        #pragma unroll
        for (int g = 0; g < NSUB; ++g) {
            cg[g] = bcnt[((b << 3) + g) * PAD];
            tot += cg[g];
        }
    }
    int s = tot;
    #pragma unroll
    for (int o = 1; o < 64; o <<= 1) {
        int t = __shfl_up(s, o);
        if (lane >= o) s += t;
    }
    int wtot = __shfl(s, 63);
    int wbase = 0;
    if (lane == 63) wbase = atomicAdd(cursor, wtot);
    wbase = __shfl(wbase, 63);
    if (b < NBKT) {
        int base = wbase + (s - tot);
        bbase[b] = base;
        btot[b]  = tot;
        int run = base;
        #pragma unroll
        for (int g = 0; g < NSUB; ++g) {
            bfill[((b << 3) + g) * PAD] = run;
            run += cg[g];
        }
    }
}

// ---------------------------------------------------------------------------
// K3: append edges to the (bucket, g) sub-frontier, g = blockIdx&7 (XCD id
// under round-robin dispatch). Frontier = 1172 partial lines (~75 KB) per
// XCD. NT loads on the 48 MB rows/cols/vals streams keep them from evicting
// the partial staging lines out of the 4 MB per-XCD L2 (round-1 lesson:
// WRITE amplification is eviction-driven, 157 MB for a 32 MB payload).
// staging element = { (local_row<<19) | col , val_bits }  (col<2^19, lr<256)
// ---------------------------------------------------------------------------
__global__ void lgcn_append(const int* __restrict__ rows, const int* __restrict__ cols,
                            const float* __restrict__ vals, int* __restrict__ bfill,
                            int2* __restrict__ staging) {
    int e = blockIdx.x * blockDim.x + threadIdx.x;
    if (e >= NNZ) return;
    int g = blockIdx.x & (NSUB - 1);
    int r   = __builtin_nontemporal_load(&rows[e]);
    int cl  = __builtin_nontemporal_load(&cols[e]);
    float v = __builtin_nontemporal_load(&vals[e]);
    int b = r >> BKT_SHIFT;
    int p = atomicAdd(&bfill[((b << 3) + g) * PAD], 1);
    staging[p] = make_int2(((r & (BKT_ROWS - 1)) << 19) | cl, __float_as_int(v));
}

// ---------------------------------------------------------------------------
// K4: per-bucket LDS sort (256 local rows). Count, block-scan, emit
// desc[row], then re-read the (L2-hot) bucket span and write row-sorted sc.
// ---------------------------------------------------------------------------
__global__ __launch_bounds__(256) void lgcn_bsort(
    const int2* __restrict__ staging, const int* __restrict__ bbase,
    const int* __restrict__ btot, int2* __restrict__ desc, int2* __restrict__ sc)
{
    __shared__ int cnt[BKT_ROWS], pfx[BKT_ROWS], fill[BKT_ROWS];
    int b   = blockIdx.x;
    int tid = threadIdx.x;
    cnt[tid] = 0;
    __syncthreads();
    int base = bbase[b];
    int n    = btot[b];

    // Phase A: count local rows (also warms the span for phase C)
    for (int i = tid; i < n; i += 256)
        atomicAdd(&cnt[staging[base + i].x >> 19], 1);
    __syncthreads();

    // Phase B: block-wide inclusive scan of 256 counts
    int c = cnt[tid];
    pfx[tid] = c;
    __syncthreads();
    for (int o = 1; o < 256; o <<= 1) {
        int t = (tid >= o) ? pfx[tid - o] : 0;
        __syncthreads();
        pfx[tid] += t;
        __syncthreads();
    }
    int excl = pfx[tid] - c;
    fill[tid] = excl;                       // relative to base
    int row = (b << BKT_SHIFT) + tid;
    if (row < N_NODES) desc[row] = make_int2(base + excl, c);
    __syncthreads();

    // Phase C: scatter into row-sorted order within the exclusive bucket span
    for (int i = tid; i < n; i += 256) {
        int2 e = staging[base + i];
        int lr = e.x >> 19;
        int p = atomicAdd(&fill[lr], 1);
        sc[base + p] = make_int2(e.x & 0x7FFFF, e.y);
    }
}

// ---------------------------------------------------------------------------
// Group-per-row CSR SpMM. Mean degree = 13.3 (Poisson): a full wave per row
// was 3-deep-latency-chain + butterfly overhead per 13 edges. Now: one row
// per 16-lane group, 4 rows/wave. Lane gl owns dims 4gl..4gl+3 (one uint2 =
// 4 bf16) of its group's row -> NO cross-lane reduction, full-wave 128B
// coalesced stores, desc/sc/gather chains of 4 rows merged into single
// instructions. Inner loop unrolled x4 -> 4 independent 512B gathers in
// flight/wave. Pad slots (c=0,v=0) read the hot row-0 line and add 0.
// NT loads on read-once streams (sc, e1, e2, own) protect bufC gather
// locality in L2.
// MODE 1: nxt = bf16x4(acc)            uint2 store    (layers 1,2)
// MODE 2: out = 0.25*(own+e1+e2+acc)   float4 store   (layer 3)
// ---------------------------------------------------------------------------
template<int MODE>
__global__ __launch_bounds__(256) void lgcn_spmm_csr(
    const int2* __restrict__ desc, const int2* __restrict__ sc,
    const uint2* __restrict__ cur2, uint2* __restrict__ nxt2,
    const float4* __restrict__ user4, const float4* __restrict__ item4,
    const uint2* __restrict__ e1b2, const uint2* __restrict__ e2b2,
    float4* __restrict__ out4)
{
    int lane = threadIdx.x & 63;
    int grp  = lane >> 4;              // 4 row-groups per wave
    int gl   = lane & 15;              // lane within group: dims 4gl..4gl+3
    int gb   = grp << 4;
    int row  = blockIdx.x * 16 + (threadIdx.x >> 6) * 4 + grp;  // exact: 18750*16=300000
    int2 d = desc[row];
    int b = d.x, n = d.y;

    // wave-uniform trip count (n is uniform within a group)
    int nmax = n;
    nmax = max(nmax, __shfl_xor(nmax, 16));
    nmax = max(nmax, __shfl_xor(nmax, 32));

    float a0lo = 0.f, a0hi = 0.f, a1lo = 0.f, a1hi = 0.f;

    for (int k0 = 0; k0 < nmax; k0 += 16) {
        int m = n - k0;                      // may be <=0 for finished groups
        int c = 0, vbits = 0;
        if (gl < m) {
            int2 cv = ntload(&sc[b + k0 + gl]);
            c = cv.x; vbits = cv.y;
        }
        int mp = min(max(m, 0), 16);
        mp = max(mp, __shfl_xor(mp, 16));
        mp = max(mp, __shfl_xor(mp, 32));
        mp = (mp + 3) & ~3;
        for (int j = 0; j < mp; j += 4) {
            int   i0 = __shfl(c, gb + j);
            int   i1 = __shfl(c, gb + j + 1);
            int   i2 = __shfl(c, gb + j + 2);
            int   i3 = __shfl(c, gb + j + 3);
            float v0 = __int_as_float(__shfl(vbits, gb + j));
            float v1 = __int_as_float(__shfl(vbits, gb + j + 1));
            float v2 = __int_as_float(__shfl(vbits, gb + j + 2));
            float v3 = __int_as_float(__shfl(vbits, gb + j + 3));
            uint2 x0 = cur2[(size_t)i0 * 16 + gl];
            uint2 x1 = cur2[(size_t)i1 * 16 + gl];
            uint2 x2 = cur2[(size_t)i2 * 16 + gl];
            uint2 x3 = cur2[(size_t)i3 * 16 + gl];
            a0lo += v0 * blo(x0.x); a0hi += v0 * bhi(x0.x);
            a1lo += v0 * blo(x0.y); a1hi += v0 * bhi(x0.y);
            a0lo += v1 * blo(x1.x); a0hi += v1 * bhi(x1.x);
            a1lo += v1 * blo(x1.y); a1hi += v1 * bhi(x1.y);
            a0lo += v2 * blo(x2.x); a0hi += v2 * bhi(x2.x);
            a1lo += v2 * blo(x2.y); a1hi += v2 * bhi(x2.y);
            a0lo += v3 * blo(x3.x); a0hi += v3 * bhi(x3.x);
            a1lo += v3 * blo(x3.y); a1hi += v3 * bhi(x3.y);
        }
    }

    if constexpr (MODE == 1) {
        uint2 o;
        o.x = ((uint32)f2bf(a0hi) << 16) | (uint32)f2bf(a0lo);
        o.y = ((uint32)f2bf(a1hi) << 16) | (uint32)f2bf(a1lo);
        nxt2[(size_t)row * 16 + gl] = o;     // 128B contiguous per group
    } else {
        const float4* ownp = (row < NUM_USERS)
            ? &user4[(size_t)row * 16 + gl]
            : &item4[(size_t)(row - NUM_USERS) * 16 + gl];
        float4 w = ntload(ownp);
        uint2 e1 = ntload(&e1b2[(size_t)row * 16 + gl]);
        uint2 e2 = ntload(&e2b2[(size_t)row * 16 + gl]);
        float4 o;
        o.x = 0.25f * (w.x + blo(e1.x) + blo(e2.x) + a0lo);
        o.y = 0.25f * (w.y + bhi(e1.x) + bhi(e2.x) + a0hi);
        o.z = 0.25f * (w.z + blo(e1.y) + blo(e2.y) + a1lo);
        o.w = 0.25f * (w.w + bhi(e1.y) + bhi(e2.y) + a1hi);
        out4[(size_t)row * 16 + gl] = o;     // 256B contiguous per group
    }
}

extern "C" void kernel_launch(void* const* d_in, const int* in_sizes, int n_in,
                              void* d_out, int out_size, void* d_ws, size_t ws_size,
                              hipStream_t stream) {
    const float* user_emb = (const float*)d_in[0];
    const float* item_emb = (const float*)d_in[1];
    const float* vals     = (const float*)d_in[2];
    const int*   rows     = (const int*)d_in[3];
    const int*   cols     = (const int*)d_in[4];
    float* out = (float*)d_out;

    // ---- workspace carve-up (~185 MB) ----
    char* ws = (char*)d_ws;
    size_t off = 0;
    unsigned short* bufC = (unsigned short*)(ws + off); off += N_ELEM * 2;      // 38.4 MB
    unsigned short* buf0 = (unsigned short*)(ws + off); off += N_ELEM * 2;      // 38.4 MB
    unsigned short* buf1 = (unsigned short*)(ws + off); off += N_ELEM * 2;      // 38.4 MB
    int2* staging = (int2*)(ws + off); off += (size_t)NNZ * 8;                  // 32 MB
    int2* sc      = (int2*)(ws + off); off += (size_t)NNZ * 8;                  // 32 MB
    int2* desc    = (int2*)(ws + off); off += (size_t)N_NODES * 8;              // 2.4 MB
    int*  bcnt    = (int*) (ws + off); off += (size_t)NBKT * NSUB * PAD * 4;    // 1.2 MB
    int*  cursor  = (int*) (ws + off); off += 256;                              // w/ bcnt memset
    int*  bbase   = (int*) (ws + off); off += (size_t)NBKT * 4;
    int*  btot    = (int*) (ws + off); off += (size_t)NBKT * 4;
    int*  bfill   = (int*) (ws + off); off += (size_t)NBKT * NSUB * PAD * 4;    // 1.2 MB

    const int BLK = 256;
    dim3 grid_conv((unsigned)((N_ELEM / 4 + BLK - 1) / BLK));   // 18750
    dim3 grid_edge((NNZ + BLK - 1) / BLK);                      // 15625
    dim3 grid_edge4((NNZ / 4 + BLK - 1) / BLK);                 // 3907
    dim3 grid_bkt((NBKT + BLK - 1) / BLK);                      // 5
    dim3 grid_sort(NBKT);                                       // 1172
    dim3 grid_spmm(N_NODES / 16);                               // 18750

    // ---- build (once per call; ws re-poisoned before every launch) ----
    (void)hipMemsetAsync(bcnt, 0, (size_t)NBKT * NSUB * PAD * 4 + 256, stream); // bcnt+cursor
    lgcn_convert<<<grid_conv, BLK, 0, stream>>>(
        (const float4*)user_emb, (const float4*)item_emb, (ushort4*)bufC);
    lgcn_bhist<<<grid_edge4, BLK, 0, stream>>>((const int4*)rows, bcnt);
    lgcn_balloc<<<grid_bkt, BLK, 0, stream>>>(bcnt, bbase, btot, bfill, cursor);
    lgcn_append<<<grid_edge, BLK, 0, stream>>>(rows, cols, vals, bfill, staging);
    lgcn_bsort<<<grid_sort, BLK, 0, stream>>>(staging, bbase, btot, desc, sc);

    // ---- 3 propagation layers ----
    lgcn_spmm_csr<1><<<grid_spmm, BLK, 0, stream>>>(
        desc, sc, (const uint2*)bufC, (uint2*)buf0,
        nullptr, nullptr, nullptr, nullptr, nullptr);
    lgcn_spmm_csr<1><<<grid_spmm, BLK, 0, stream>>>(
        desc, sc, (const uint2*)buf0, (uint2*)buf1,
        nullptr, nullptr, nullptr, nullptr, nullptr);
    lgcn_spmm_csr<2><<<grid_spmm, BLK, 0, stream>>>(
        desc, sc, (const uint2*)buf1, nullptr,
        (const float4*)user_emb, (const float4*)item_emb,
        (const uint2*)buf0, (const uint2*)buf1, (float4*)out);
}